// Round 4
// baseline (60.331 us; speedup 1.0000x reference)
//
#include <hip/hip_runtime.h>
#include <hip/hip_bf16.h>

// Single fused kernel. Grid 512 = 64 m-tiles(128 px) x 8 n-tiles(4 o).
// Per block (256 thr, 4 waves): wave w owns output channel o = nt*4+w.
//   B-frags (W2 slice, 2 nf x 9 kb) live in registers, gathered coalesced
//   from native fp32 W2. Waves 0,1 carry W1 (hh), wave 2 carries b2 (t) as
//   one extra B-frag. Two 64-pixel subtiles: x rows -> LDS -> bf16 u tile ->
//   MFMA K-loop -> hh/t to LDS -> h-contraction epilogue -> coalesced store.

#define CKK 288
#define SJ  296   // u_lds row stride in bf16 (592B: 2-way-free b128 reads)

typedef __attribute__((ext_vector_type(8))) short short8;
typedef __attribute__((ext_vector_type(4))) short short4v;
typedef __attribute__((ext_vector_type(4))) float f32x4;

__device__ __forceinline__ short f2bf(float f) {
    __hip_bfloat16 h = __float2bfloat16(f);
    return __builtin_bit_cast(short, h);
}

__global__ __launch_bounds__(256, 2) void dynaconv_one(
    const float* __restrict__ x,    // [2,32,64,64]
    const float* __restrict__ W1,   // [32,288]
    const float* __restrict__ b1,   // [32]
    const float* __restrict__ W2,   // [9216,32]
    const float* __restrict__ b2,   // [9216]
    const float* __restrict__ bias, // [32]
    float* __restrict__ out)        // [2,32,4096]
{
    __shared__ __align__(16) float x_lds[3][32][66];          // ky, c, wx(-1..64)
    __shared__ __align__(16) __hip_bfloat16 u_lds[64 * SJ];   // [p][j]
    __shared__ float hh_lds[64 * 33];                         // [p][h]
    __shared__ float t_lds[64 * 4];                           // [p][o_local]
    __shared__ float o_stage[4][64];                          // [wave][p]

    const int t  = threadIdx.x;
    const int w  = t >> 6, l = t & 63, lg = l >> 4, lr = l & 15;
    const int nt = blockIdx.x & 7, mt = blockIdx.x >> 3;
    const int o_w = nt * 4 + w;       // this wave's output channel

    // ---- one-time B-gather into registers ----
    short8 breg[9][2];
    #pragma unroll
    for (int nf = 0; nf < 2; ++nf) {
        const int h = nf * 16 + lr;
        const size_t base = (size_t)o_w * CKK * 32 + h;
        #pragma unroll
        for (int kb = 0; kb < 9; ++kb) {
            short8 v;
            #pragma unroll
            for (int i = 0; i < 8; ++i) {
                int j = kb * 32 + lg * 8 + i;
                v[i] = f2bf(W2[base + (size_t)j * 32]);   // lanes lr: consecutive 4B
            }
            breg[kb][nf] = v;
        }
    }
    short8 ereg[9];
    if (w < 2) {                       // W1 rows h = w*16+lr
        const int h = w * 16 + lr;
        #pragma unroll
        for (int kb = 0; kb < 9; ++kb) {
            short8 v;
            #pragma unroll
            for (int i = 0; i < 8; ++i)
                v[i] = f2bf(W1[h * CKK + kb * 32 + lg * 8 + i]);
            ereg[kb] = v;
        }
    } else if (w == 2) {               // b2 rows o_local = lr (<4)
        #pragma unroll
        for (int kb = 0; kb < 9; ++kb) {
            short8 v;
            #pragma unroll
            for (int i = 0; i < 8; ++i) {
                float f = (lr < 4) ? b2[(nt * 4 + lr) * CKK + kb * 32 + lg * 8 + i] : 0.f;
                v[i] = f2bf(f);
            }
            ereg[kb] = v;
        }
    } else {
        #pragma unroll
        for (int kb = 0; kb < 9; ++kb) ereg[kb] = short8{0,0,0,0,0,0,0,0};
    }

    // ---- two 64-pixel subtiles (each = one image row) ----
    for (int sub = 0; sub < 2; ++sub) {
        const int row = mt * 2 + sub;   // 0..127
        const int b   = row >> 6;
        const int y   = row & 63;

        __syncthreads();                // protect x_lds/u_lds from prev readers
        #pragma unroll
        for (int k = 0; k < 24; ++k) {  // 6144 floats, coalesced
            int idx = k * 256 + t;
            int ky  = idx >> 11;
            int rem = idx & 2047;
            int c   = rem >> 6;
            int wx  = rem & 63;
            int yy  = y + ky - 1;
            float v = 0.f;
            if ((unsigned)yy < 64u)
                v = x[((b * 32 + c) * 64 + yy) * 64 + wx];
            x_lds[ky][c][wx + 1] = v;
        }
        if (t < 96) {                   // zero halo columns
            int ky = t / 32, c = t & 31;
            x_lds[ky][c][0]  = 0.f;
            x_lds[ky][c][65] = 0.f;
        }
        __syncthreads();

        // repack -> u_lds[p][j], thread = (p = t&63, j-range jq*72..+72)
        {
            const int p = t & 63, jq = t >> 6;
            #pragma unroll
            for (int j4 = 0; j4 < 18; ++j4) {
                short4v sv;
                #pragma unroll
                for (int e = 0; e < 4; ++e) {
                    int j  = jq * 72 + j4 * 4 + e;
                    int c  = j / 9, r = j - c * 9;
                    int ki = r / 3, kj = r - ki * 3;
                    sv[e] = f2bf(x_lds[ki][c][p + kj]);
                }
                *(short4v*)(u_lds + p * SJ + jq * 72 + j4 * 4) = sv;
            }
        }
        __syncthreads();

        // MFMA K-loop: acc = S (2 nf), acce = W1/b2 extra frag
        f32x4 acc[4][2], acce[4];
        #pragma unroll
        for (int mf = 0; mf < 4; ++mf) {
            acc[mf][0] = f32x4{0.f,0.f,0.f,0.f};
            acc[mf][1] = f32x4{0.f,0.f,0.f,0.f};
            acce[mf]   = f32x4{0.f,0.f,0.f,0.f};
        }
        #pragma unroll
        for (int kb = 0; kb < 9; ++kb) {
            short8 a[4];
            #pragma unroll
            for (int mf = 0; mf < 4; ++mf)
                a[mf] = *(const short8*)(u_lds + (mf * 16 + lr) * SJ + kb * 32 + lg * 8);
            #pragma unroll
            for (int mf = 0; mf < 4; ++mf) {
                acc[mf][0] = __builtin_amdgcn_mfma_f32_16x16x32_bf16(a[mf], breg[kb][0], acc[mf][0], 0, 0, 0);
                acc[mf][1] = __builtin_amdgcn_mfma_f32_16x16x32_bf16(a[mf], breg[kb][1], acc[mf][1], 0, 0, 0);
            }
            if (w < 3) {
                #pragma unroll
                for (int mf = 0; mf < 4; ++mf)
                    acce[mf] = __builtin_amdgcn_mfma_f32_16x16x32_bf16(a[mf], ereg[kb], acce[mf], 0, 0, 0);
            }
        }

        // owners publish hh (tanh) and t (+bias)
        if (w < 2) {
            const int h = w * 16 + lr;
            const float b1v = b1[h];
            #pragma unroll
            for (int mf = 0; mf < 4; ++mf)
                #pragma unroll
                for (int r = 0; r < 4; ++r)
                    hh_lds[(mf * 16 + lg * 4 + r) * 33 + h] = tanhf(acce[mf][r] + b1v);
        } else if (w == 2 && lr < 4) {
            const float bv = bias[nt * 4 + lr];
            #pragma unroll
            for (int mf = 0; mf < 4; ++mf)
                #pragma unroll
                for (int r = 0; r < 4; ++r)
                    t_lds[(mf * 16 + lg * 4 + r) * 4 + lr] = acce[mf][r] + bv;
        }
        __syncthreads();

        // epilogue: out[p, o_w] = sum_h hh[p,h] * S[p, o_w*32+h]
        #pragma unroll
        for (int mf = 0; mf < 4; ++mf) {
            #pragma unroll
            for (int r = 0; r < 4; ++r) {
                const int p = mf * 16 + lg * 4 + r;
                float v = hh_lds[p * 33 + lr]      * acc[mf][0][r]
                        + hh_lds[p * 33 + 16 + lr] * acc[mf][1][r];
                v += __shfl_xor(v, 1);
                v += __shfl_xor(v, 2);
                v += __shfl_xor(v, 4);
                v += __shfl_xor(v, 8);
                if (lr == 0) o_stage[w][p] = v;
            }
        }
        float res = o_stage[w][l] + t_lds[l * 4 + w];   // same-wave LDS, ordered
        out[((size_t)(b * 32 + o_w)) * 4096 + y * 64 + l] = res;
    }
}

extern "C" void kernel_launch(void* const* d_in, const int* in_sizes, int n_in,
                              void* d_out, int out_size, void* d_ws, size_t ws_size,
                              hipStream_t stream) {
    const float* x    = (const float*)d_in[0];
    const float* W1   = (const float*)d_in[1];
    const float* b1   = (const float*)d_in[2];
    const float* W2   = (const float*)d_in[3];
    const float* b2   = (const float*)d_in[4];
    const float* bias = (const float*)d_in[5];
    float* out = (float*)d_out;

    dynaconv_one<<<512, 256, 0, stream>>>(x, W1, b1, W2, b2, bias, out);
}

// Round 6
// 35.540 us; speedup vs baseline: 1.6975x; 1.6975x over previous
//
#include <hip/hip_runtime.h>
#include <hip/hip_bf16.h>

// R2 structure (proven correct), one change: W2b stored in B-FRAGMENT order
//   W2f[((o*2+nf)*9 + kb)*512 + l*8 + e] = W2[(o*288 + kb*32 + (l>>4)*8 + e)*32
//                                             + nf*16 + (l&15)]
// so main's B loads are 64-lane contiguous 1KB bursts instead of 576B-strided
// 16B gathers (4x less L2 traffic, 16x fewer transactions).

#define CKK 288
#define SJ  296   // padded j-stride for u_lds (bf16 elems)

typedef __attribute__((ext_vector_type(8))) short short8;
typedef __attribute__((ext_vector_type(4))) float f32x4;

// ws layout in bf16 elements
#define W2F_OFF 0               // [64 w8][9 kb][64 lane][8] fragment order
#define W1B_OFF 294912          // [32][288] row order
#define B2B_OFF (294912 + 9216) // [32][288] row order
#define WS_ELEMS (294912 + 9216 + 9216)

__global__ __launch_bounds__(256) void prep_kernel(
    const float* __restrict__ W1, const float* __restrict__ W2,
    const float* __restrict__ b2, __hip_bfloat16* __restrict__ ws)
{
    int idx = blockIdx.x * 256 + threadIdx.x;
    if (idx < 294912) {
        // dest = fragment order; src gather identical pattern to R2's prep
        int e  = idx & 7;
        int l  = (idx >> 3) & 63;
        int ck = idx >> 9;              // 0..575 = w8*9 + kb
        int w8 = ck / 9, kb = ck - w8 * 9;
        int o  = w8 >> 1;
        int h  = (w8 & 1) * 16 + (l & 15);
        int j  = kb * 32 + ((l >> 4) << 3) + e;
        ws[W2F_OFF + idx] = __float2bfloat16(W2[(o * CKK + j) * 32 + h]);
    } else if (idx < 294912 + 9216) {
        int k = idx - 294912;
        ws[W1B_OFF + k] = __float2bfloat16(W1[k]);
    } else if (idx < WS_ELEMS) {
        int k = idx - (294912 + 9216);
        ws[B2B_OFF + k] = __float2bfloat16(b2[k]);
    }
}

__global__ __launch_bounds__(512) void dynaconv_main(
    const float* __restrict__ x,     // [2,32,64,64]
    const float* __restrict__ b1,    // [32]
    const float* __restrict__ bias,  // [32]
    const __hip_bfloat16* __restrict__ ws,
    float* __restrict__ out)         // [2,32,4096]
{
    __shared__ __hip_bfloat16 u_lds[32 * SJ];  // [p][j]
    __shared__ float hh_lds[32 * 33];          // [p][h]
    __shared__ float o_lds[32 * 33];           // [p][o], seeded with t+bias

    const int t  = threadIdx.x;
    const int w  = t >> 6;   // wave 0..7
    const int l  = t & 63;
    const int lg = l >> 4;   // k-group 0..3
    const int lr = l & 15;

    const int g0  = blockIdx.x * 32;  // first global pixel
    const int b   = g0 >> 12;
    const int l0  = g0 & 4095;
    const int y   = l0 >> 6;
    const int wx0 = l0 & 63;

    // ---- Phase A: fused unfold -> u_lds (bf16) ----
    #pragma unroll
    for (int k = 0; k < 18; ++k) {
        int idx = k * 512 + t;        // 9216 = 32p * 288j
        int j = idx >> 5, p = idx & 31;
        int c = j / 9, r = j - c * 9;
        int ki = r / 3, kj = r - ki * 3;
        int y2 = y + ki - 1;
        int x2 = wx0 + p + kj - 1;
        float v = 0.f;
        if ((unsigned)y2 < 64u && (unsigned)x2 < 64u)
            v = x[((b * 32 + c) * 64 + y2) * 64 + x2];
        u_lds[p * SJ + j] = __float2bfloat16(v);
    }
    __syncthreads();

    // ---- Phase B: waves 0-1: t+bias -> o_lds ; waves 2-3: hh -> hh_lds ----
    if (w < 4) {
        const __hip_bfloat16* Bmat = ws + ((w < 2) ? B2B_OFF : W1B_OFF);
        const int col = ((w & 1) * 16) + lr;   // o or h column
        f32x4 acc0 = {0.f, 0.f, 0.f, 0.f}, acc1 = {0.f, 0.f, 0.f, 0.f};
        #pragma unroll
        for (int kb = 0; kb < 9; ++kb) {
            short8 bf = *(const short8*)(Bmat + col * CKK + kb * 32 + lg * 8);
            short8 a0 = *(const short8*)(u_lds + lr * SJ + kb * 32 + lg * 8);
            short8 a1 = *(const short8*)(u_lds + (16 + lr) * SJ + kb * 32 + lg * 8);
            acc0 = __builtin_amdgcn_mfma_f32_16x16x32_bf16(a0, bf, acc0, 0, 0, 0);
            acc1 = __builtin_amdgcn_mfma_f32_16x16x32_bf16(a1, bf, acc1, 0, 0, 0);
        }
        if (w < 2) {
            float bv = bias[col];
            #pragma unroll
            for (int r = 0; r < 4; ++r) {
                o_lds[(lg * 4 + r) * 33 + col]        = acc0[r] + bv;
                o_lds[(16 + lg * 4 + r) * 33 + col]   = acc1[r] + bv;
            }
        } else {
            float b1v = b1[col];
            #pragma unroll
            for (int r = 0; r < 4; ++r) {
                hh_lds[(lg * 4 + r) * 33 + col]       = tanhf(acc0[r] + b1v);
                hh_lds[(16 + lg * 4 + r) * 33 + col]  = tanhf(acc1[r] + b1v);
            }
        }
    }
    __syncthreads();

    // ---- Phase C: main GEMM. wave w owns o = w*4..w*4+3 -> n = w*128..+127 ----
    f32x4 acc[2][8];
    #pragma unroll
    for (int m = 0; m < 2; ++m)
        #pragma unroll
        for (int nf = 0; nf < 8; ++nf)
            acc[m][nf] = f32x4{0.f, 0.f, 0.f, 0.f};

    {
        const __hip_bfloat16* W2f = ws + W2F_OFF;
        // fragment-order loads: chunk (w*8+nf)*9+kb, 64 lanes x 16B contiguous
        short8 bcur[8];
        #pragma unroll
        for (int nf = 0; nf < 8; ++nf)
            bcur[nf] = *(const short8*)(W2f + (size_t)((w * 8 + nf) * 9 + 0) * 512 + l * 8);

        #pragma unroll
        for (int kb = 0; kb < 9; ++kb) {
            short8 a0 = *(const short8*)(u_lds + lr * SJ + kb * 32 + lg * 8);
            short8 a1 = *(const short8*)(u_lds + (16 + lr) * SJ + kb * 32 + lg * 8);
            short8 bnext[8];
            if (kb < 8) {
                #pragma unroll
                for (int nf = 0; nf < 8; ++nf)
                    bnext[nf] = *(const short8*)(W2f + (size_t)((w * 8 + nf) * 9 + kb + 1) * 512 + l * 8);
            }
            #pragma unroll
            for (int nf = 0; nf < 8; ++nf) {
                acc[0][nf] = __builtin_amdgcn_mfma_f32_16x16x32_bf16(a0, bcur[nf], acc[0][nf], 0, 0, 0);
                acc[1][nf] = __builtin_amdgcn_mfma_f32_16x16x32_bf16(a1, bcur[nf], acc[1][nf], 0, 0, 0);
            }
            if (kb < 8) {
                #pragma unroll
                for (int nf = 0; nf < 8; ++nf)
                    bcur[nf] = bnext[nf];
            }
        }
    }

    // ---- Epilogue: out[p,o] = sum_h hh[p,h]*S[p,o,h]  (+ t+bias in o_lds) ----
    #pragma unroll
    for (int ol = 0; ol < 4; ++ol) {
        const int o = w * 4 + ol;
        #pragma unroll
        for (int m = 0; m < 2; ++m) {
            #pragma unroll
            for (int r = 0; r < 4; ++r) {
                const int p = m * 16 + lg * 4 + r;
                float v = hh_lds[p * 33 + lr]      * acc[m][ol * 2][r]
                        + hh_lds[p * 33 + 16 + lr] * acc[m][ol * 2 + 1][r];
                v += __shfl_xor(v, 1);
                v += __shfl_xor(v, 2);
                v += __shfl_xor(v, 4);
                v += __shfl_xor(v, 8);
                if (lr == 0) o_lds[p * 33 + o] += v;
            }
        }
    }
    __syncthreads();

    // ---- Store: coalesced over p ----
    #pragma unroll
    for (int k = 0; k < 2; ++k) {
        int idx = k * 512 + t;          // 1024 = 32o * 32p
        int o = idx >> 5, p = idx & 31;
        out[((size_t)(b * 32 + o)) * 4096 + l0 + p] = o_lds[p * 33 + o];
    }
}

extern "C" void kernel_launch(void* const* d_in, const int* in_sizes, int n_in,
                              void* d_out, int out_size, void* d_ws, size_t ws_size,
                              hipStream_t stream) {
    const float* x    = (const float*)d_in[0];
    const float* W1   = (const float*)d_in[1];
    const float* b1   = (const float*)d_in[2];
    const float* W2   = (const float*)d_in[3];
    const float* b2   = (const float*)d_in[4];
    const float* bias = (const float*)d_in[5];
    float* out = (float*)d_out;
    __hip_bfloat16* ws = (__hip_bfloat16*)d_ws;

    prep_kernel<<<(WS_ELEMS + 255) / 256, 256, 0, stream>>>(W1, W2, b2, ws);
    dynaconv_main<<<256, 512, 0, stream>>>(x, b1, bias, ws, out);
}